// Round 11
// baseline (133.648 us; speedup 1.0000x reference)
//
#include <hip/hip_runtime.h>
#include <hip/hip_bf16.h>

#define H_HEADS 8
#define D_OUT 16
#define C_FEATS 128          // H*D = in-feats = 128
#define NEG_SLOPE 0.2f

typedef __attribute__((ext_vector_type(8))) short short8;
typedef __attribute__((ext_vector_type(4))) float f32x4;

__device__ inline unsigned short f2bf(float f) {
    __hip_bfloat16 b = __float2bfloat16(f);
    return *reinterpret_cast<unsigned short*>(&b);
}
__device__ inline float bf2f(unsigned short u) {
    return __uint_as_float((unsigned)u << 16);
}
__device__ inline float bf_lo(unsigned u) { return __uint_as_float(u << 16); }
__device__ inline float bf_hi(unsigned u) { return __uint_as_float(u & 0xffff0000u); }

// ---------------- prologue: W -> split-bf16 fragment layout; zero deg -------
__global__ __launch_bounds__(256) void k_prep(const float* __restrict__ W,
                                              unsigned short* __restrict__ Wfh,
                                              unsigned short* __restrict__ Wfl,
                                              int* __restrict__ deg, int N) {
    const int b = blockIdx.x, t = threadIdx.x;
    if (b < 8) {
        const int idx = b * 256 + t;          // 0..2047 = 32 frags x 64 lanes
        const int frag = idx >> 6, lane = idx & 63;
        const int kc = frag >> 3, nt = frag & 7;
        const int kb = kc * 32 + ((lane >> 4) << 3);
        const int col = nt * 16 + (lane & 15);
        unsigned short hs[8], ls[8];
#pragma unroll
        for (int i = 0; i < 8; ++i) {
            const float x = W[(size_t)(kb + i) * C_FEATS + col];
            const unsigned short hh = f2bf(x);
            hs[i] = hh;
            ls[i] = f2bf(x - bf2f(hh));
        }
        uint4 uh, ul;
        uh.x = hs[0] | ((unsigned)hs[1] << 16);
        uh.y = hs[2] | ((unsigned)hs[3] << 16);
        uh.z = hs[4] | ((unsigned)hs[5] << 16);
        uh.w = hs[6] | ((unsigned)hs[7] << 16);
        ul.x = ls[0] | ((unsigned)ls[1] << 16);
        ul.y = ls[2] | ((unsigned)ls[3] << 16);
        ul.z = ls[4] | ((unsigned)ls[5] << 16);
        ul.w = ls[6] | ((unsigned)ls[7] << 16);
        *reinterpret_cast<uint4*>(&Wfh[(size_t)idx * 8]) = uh;
        *reinterpret_cast<uint4*>(&Wfl[(size_t)idx * 8]) = ul;
    } else {
        const int i = (b - 8) * 256 + t;
        if (i < N) deg[i] = 0;
    }
}

// ---------------- degree + rank (standalone, no LDS, full occupancy) --------
__global__ __launch_bounds__(256) void k_deg_rank(const int* __restrict__ dst,
                                                  int* __restrict__ deg,
                                                  int* __restrict__ rank, int E) {
    const int e = blockIdx.x * 256 + threadIdx.x;
    if (e < E)
        rank[e] = atomicAdd(&deg[dst[e]], 1);
}

// ---------------- MFMA GEMM, LDS-staged W, fused logits epilogue ------------
// 512 threads = 8 waves, 128 rows/block. Wfh+Wfl (64KB) staged to LDS once.
// Epilogue: h16 stores + es/ed from acc registers (16-lane shfl reduction;
// head nt's 16 dims are exactly the wave's 16-lane column group).
__global__ __launch_bounds__(512) void k_gemm(
    const float* __restrict__ feat, const unsigned short* __restrict__ Wfh,
    const unsigned short* __restrict__ Wfl, const float* __restrict__ aw,
    unsigned short* __restrict__ h16, float* __restrict__ es,
    float* __restrict__ ed, int N) {
    const int t = threadIdx.x;
    __shared__ uint4 sW[4096];                 // [0,2048): Wfh  [2048,4096): Wfl
    {
        const uint4* gh = reinterpret_cast<const uint4*>(Wfh);
        const uint4* gl = reinterpret_cast<const uint4*>(Wfl);
#pragma unroll
        for (int i = 0; i < 4; ++i) {
            const int j = t + i * 512;
            sW[j] = gh[j];
            sW[j + 2048] = gl[j];
        }
    }
    __syncthreads();

    const int bid = blockIdx.x;
    const int w = t >> 6, lane = t & 63;
    const int rbase = bid * 128 + w * 16;
    const int rowA = rbase + (lane & 15);
    const int ko = (lane >> 4) << 3;
    const bool rv = rowA < N;
    const float* fr = feat + (size_t)rowA * C_FEATS;

    f32x4 acc[8];
#pragma unroll
    for (int nt = 0; nt < 8; ++nt)
#pragma unroll
        for (int j = 0; j < 4; ++j) acc[nt][j] = 0.f;

#pragma unroll
    for (int kc = 0; kc < 4; ++kc) {
        float4 x0 = make_float4(0.f, 0.f, 0.f, 0.f), x1 = x0;
        if (rv) {
            x0 = *reinterpret_cast<const float4*>(fr + kc * 32 + ko);
            x1 = *reinterpret_cast<const float4*>(fr + kc * 32 + ko + 4);
        }
        const float xs[8] = {x0.x, x0.y, x0.z, x0.w, x1.x, x1.y, x1.z, x1.w};
        short8 ah, al;
#pragma unroll
        for (int i = 0; i < 8; ++i) {
            const unsigned short hh = f2bf(xs[i]);
            ah[i] = (short)hh;
            al[i] = (short)f2bf(xs[i] - bf2f(hh));
        }
#pragma unroll
        for (int nt = 0; nt < 8; ++nt) {
            const int fi = (kc * 8 + nt) * 64 + lane;
            const short8 bh = *reinterpret_cast<const short8*>(&sW[fi]);
            const short8 bl = *reinterpret_cast<const short8*>(&sW[fi + 2048]);
            acc[nt] = __builtin_amdgcn_mfma_f32_16x16x32_bf16(ah, bh, acc[nt], 0, 0, 0);
            acc[nt] = __builtin_amdgcn_mfma_f32_16x16x32_bf16(al, bh, acc[nt], 0, 0, 0);
            acc[nt] = __builtin_amdgcn_mfma_f32_16x16x32_bf16(ah, bl, acc[nt], 0, 0, 0);
        }
    }
    // C layout (verified): col = lane&15, row = (lane>>4)*4 + reg
    const int r0 = rbase + ((lane >> 4) << 2);
    const int colc = lane & 15;
#pragma unroll
    for (int nt = 0; nt < 8; ++nt) {
#pragma unroll
        for (int r = 0; r < 4; ++r) {
            const int row = r0 + r;
            if (row < N)
                h16[(size_t)row * C_FEATS + nt * 16 + colc] = f2bf(acc[nt][r]);
        }
    }
    // logits epilogue: es/ed[row, nt] = sum_d acc-col-group * aw
#pragma unroll
    for (int nt = 0; nt < 8; ++nt) {
        const float wa = aw[nt * 16 + colc];
        const float wb = aw[C_FEATS + nt * 16 + colc];
#pragma unroll
        for (int r = 0; r < 4; ++r) {
            float pe = acc[nt][r] * wa;
            float pd = acc[nt][r] * wb;
#pragma unroll
            for (int msk = 1; msk <= 8; msk <<= 1) {
                pe += __shfl_xor(pe, msk, 64);
                pd += __shfl_xor(pd, msk, 64);
            }
            const int row = r0 + r;
            if (colc == 0 && row < N) {
                es[(size_t)row * H_HEADS + nt] = pe;
                ed[(size_t)row * H_HEADS + nt] = pd;
            }
        }
    }
}

// ---------------- per-block degree sums ----------------
__global__ void k_bsum(const int* __restrict__ deg, int* __restrict__ bsum, int N) {
    int i = blockIdx.x * 256 + threadIdx.x;
    int v = (i < N) ? deg[i] : 0;
#pragma unroll
    for (int m = 1; m < 64; m <<= 1) v += __shfl_xor(v, m, 64);
    __shared__ int ws[4];
    if ((threadIdx.x & 63) == 0) ws[threadIdx.x >> 6] = v;
    __syncthreads();
    if (threadIdx.x == 0) bsum[blockIdx.x] = ws[0] + ws[1] + ws[2] + ws[3];
}

// ---------------- scan helpers ----------------
__device__ inline int block_scan_incl(int v) {
    int lane = threadIdx.x & 63, w = threadIdx.x >> 6;
    int x = v;
#pragma unroll
    for (int d = 1; d < 64; d <<= 1) {
        int u = __shfl_up(x, d, 64);
        if (lane >= d) x += u;
    }
    __shared__ int wsum[4];
    if (lane == 63) wsum[w] = x;
    __syncthreads();
    int add = 0;
    for (int k = 0; k < w; ++k) add += wsum[k];
    return x + add;
}

__global__ void k_scanb(const int* __restrict__ bsum, int* __restrict__ bpre,
                        int NB, int* __restrict__ offs, int N) {
    int t = threadIdx.x;
    int v = (t < NB) ? bsum[t] : 0;
    int incl = block_scan_incl(v);
    if (t < NB) bpre[t] = incl - v;
    if (t == NB - 1) offs[N] = incl;
}

__global__ void k_scanc(const int* __restrict__ deg, const int* __restrict__ bpre,
                        int* __restrict__ offs, int N) {
    int i = blockIdx.x * 256 + threadIdx.x;
    int v = (i < N) ? deg[i] : 0;
    int incl = block_scan_incl(v);
    int excl = incl - v + bpre[blockIdx.x];
    if (i < N) offs[i] = excl;
}

// ---------------- scatter: atomic-free via precomputed ranks ----------------
__global__ void k_scatter(const int* __restrict__ src, const int* __restrict__ dst,
                          const int* __restrict__ rank, const int* __restrict__ offs,
                          int* __restrict__ ssorted, int E) {
    int e = blockIdx.x * 256 + threadIdx.x;
    if (e < E)
        ssorted[offs[dst[e]] + rank[e]] = src[e];
}

// ---------------- two-pass softmax + aggregation (R8-proven, untouched) -----
__global__ __launch_bounds__(256) void k_agg(const unsigned short* __restrict__ h16,
                                             const float* __restrict__ es,
                                             const float* __restrict__ ed,
                                             const int* __restrict__ offs,
                                             const int* __restrict__ ssorted,
                                             const float* __restrict__ bias,
                                             float* __restrict__ out, int N) {
    const int wid = threadIdx.x >> 6, lane = threadIdx.x & 63;
    const int n = blockIdx.x * 4 + wid;
    if (n >= N) return;
    const int beg = offs[n];
    const int deg = offs[n + 1] - beg;

    const int hh = lane >> 3, j0 = lane & 7;
    const float edv = ed[(size_t)n * H_HEADS + hh];

    const int cl = lane & 15, q = lane >> 4;
    const int ah = cl >> 1;             // head owning this lane's 8 columns
    const int ab = ah << 3;             // softmax-layout base lane for head ah
    float acc[8];
#pragma unroll
    for (int k = 0; k < 8; ++k) acc[k] = 0.f;

    float m = -1e30f, s = 0.f;

    if (deg <= 32) {
        // ---------- cached fast path ----------
        int snc[4];
        float evc[4];
#pragma unroll
        for (int c = 0; c < 4; ++c) {
            const int j = c * 8 + j0;
            const bool va = (j < deg);
            int sn = 0;
            float ev = -1e30f;
            if (va) {
                sn = ssorted[beg + j];
                float t = es[(size_t)sn * H_HEADS + hh] + edv;
                ev = t > 0.f ? t : NEG_SLOPE * t;
                if (ev > m) {
                    s = s * __expf(m - ev) + 1.f;
                    m = ev;
                } else {
                    s += __expf(ev - m);
                }
            }
            snc[c] = sn;
            evc[c] = ev;
        }
#pragma unroll
        for (int msk = 1; msk < 8; msk <<= 1) {
            float mo = __shfl_xor(m, msk, 64);
            float so = __shfl_xor(s, msk, 64);
            float mn = fmaxf(m, mo);
            s = s * __expf(m - mn) + so * __expf(mo - mn);
            m = mn;
        }
        const float inv = (s > 0.f) ? 1.f / s : 0.f;

#pragma unroll
        for (int c = 0; c < 4; ++c) {
            const int cb = c * 8;
            if (cb >= deg) break;                 // wave-uniform exit
            const float alpha = (cb + j0 < deg) ? __expf(evc[c] - m) * inv : 0.f;
            const int sn = snc[c];
            int rem = deg - cb; if (rem > 8) rem = 8;
#pragma unroll
            for (int e4 = 0; e4 < 2; ++e4) {
                if (4 * e4 >= rem) break;         // wave-uniform exit
                const int s0 = __shfl(sn, 4 * e4 + 0, 64);
                const int s1 = __shfl(sn, 4 * e4 + 1, 64);
                const int s2 = __shfl(sn, 4 * e4 + 2, 64);
                const int s3 = __shfl(sn, 4 * e4 + 3, 64);
                const int snq = (q == 0) ? s0 : (q == 1) ? s1 : (q == 2) ? s2 : s3;
                const float al = __shfl(alpha, ab + 4 * e4 + q, 64);
                const uint4 hv = *reinterpret_cast<const uint4*>(
                    &h16[(size_t)snq * C_FEATS + cl * 8]);
                acc[0] = fmaf(al, bf_lo(hv.x), acc[0]);
                acc[1] = fmaf(al, bf_hi(hv.x), acc[1]);
                acc[2] = fmaf(al, bf_lo(hv.y), acc[2]);
                acc[3] = fmaf(al, bf_hi(hv.y), acc[3]);
                acc[4] = fmaf(al, bf_lo(hv.z), acc[4]);
                acc[5] = fmaf(al, bf_hi(hv.z), acc[5]);
                acc[6] = fmaf(al, bf_lo(hv.w), acc[6]);
                acc[7] = fmaf(al, bf_hi(hv.w), acc[7]);
            }
        }
    } else {
        // ---------- streaming fallback ----------
        for (int e = j0; e < deg; e += 8) {
            int sn = ssorted[beg + e];
            float ev = es[(size_t)sn * H_HEADS + hh] + edv;
            ev = ev > 0.f ? ev : NEG_SLOPE * ev;
            if (ev > m) {
                s = s * __expf(m - ev) + 1.f;
                m = ev;
            } else {
                s += __expf(ev - m);
            }
        }
#pragma unroll
        for (int msk = 1; msk < 8; msk <<= 1) {
            float mo = __shfl_xor(m, msk, 64);
            float so = __shfl_xor(s, msk, 64);
            float mn = fmaxf(m, mo);
            s = s * __expf(m - mn) + so * __expf(mo - mn);
            m = mn;
        }
        const float inv = (s > 0.f) ? 1.f / s : 0.f;

        for (int cb = 0; cb < deg; cb += 8) {
            const int j = cb + j0;
            int sn = 0;
            float alpha = 0.f;
            if (j < deg) {
                sn = ssorted[beg + j];
                float t = es[(size_t)sn * H_HEADS + hh] + edv;
                t = t > 0.f ? t : NEG_SLOPE * t;
                alpha = __expf(t - m) * inv;
            }
            int rem = deg - cb; if (rem > 8) rem = 8;
#pragma unroll
            for (int e4 = 0; e4 < 2; ++e4) {
                if (4 * e4 >= rem) break;
                const int s0 = __shfl(sn, 4 * e4 + 0, 64);
                const int s1 = __shfl(sn, 4 * e4 + 1, 64);
                const int s2 = __shfl(sn, 4 * e4 + 2, 64);
                const int s3 = __shfl(sn, 4 * e4 + 3, 64);
                const int snq = (q == 0) ? s0 : (q == 1) ? s1 : (q == 2) ? s2 : s3;
                const float al = __shfl(alpha, ab + 4 * e4 + q, 64);
                const uint4 hv = *reinterpret_cast<const uint4*>(
                    &h16[(size_t)snq * C_FEATS + cl * 8]);
                acc[0] = fmaf(al, bf_lo(hv.x), acc[0]);
                acc[1] = fmaf(al, bf_hi(hv.x), acc[1]);
                acc[2] = fmaf(al, bf_lo(hv.y), acc[2]);
                acc[3] = fmaf(al, bf_hi(hv.y), acc[3]);
                acc[4] = fmaf(al, bf_lo(hv.z), acc[4]);
                acc[5] = fmaf(al, bf_hi(hv.z), acc[5]);
                acc[6] = fmaf(al, bf_lo(hv.w), acc[6]);
                acc[7] = fmaf(al, bf_hi(hv.w), acc[7]);
            }
        }
    }

#pragma unroll
    for (int k = 0; k < 8; ++k) {
        acc[k] += __shfl_xor(acc[k], 16, 64);
        acc[k] += __shfl_xor(acc[k], 32, 64);
    }
    if (q == 0) {
        const float4 b0 = *reinterpret_cast<const float4*>(&bias[cl * 8]);
        const float4 b1 = *reinterpret_cast<const float4*>(&bias[cl * 8 + 4]);
        float4 o0 = make_float4(acc[0] + b0.x, acc[1] + b0.y, acc[2] + b0.z, acc[3] + b0.w);
        float4 o1 = make_float4(acc[4] + b1.x, acc[5] + b1.y, acc[6] + b1.z, acc[7] + b1.w);
        *reinterpret_cast<float4*>(&out[(size_t)n * C_FEATS + cl * 8]) = o0;
        *reinterpret_cast<float4*>(&out[(size_t)n * C_FEATS + cl * 8 + 4]) = o1;
    }
}

extern "C" void kernel_launch(void* const* d_in, const int* in_sizes, int n_in,
                              void* d_out, int out_size, void* d_ws, size_t ws_size,
                              hipStream_t stream) {
    const float* feat = (const float*)d_in[0];
    const float* W    = (const float*)d_in[1];
    const float* aw   = (const float*)d_in[2];
    const float* bias = (const float*)d_in[3];
    const int*   src  = (const int*)d_in[4];
    const int*   dst  = (const int*)d_in[5];
    float* out = (float*)d_out;

    const int N = in_sizes[0] / C_FEATS;
    const int E = in_sizes[4];
    const int NB = (N + 255) / 256;          // 196 (<= 256 for k_scanb)
    const int GB = (N + 127) / 128;          // gemm blocks (391)
    const int EB = (E + 255) / 256;          // edge blocks (3125)

    char* p = (char*)d_ws;
    auto take = [&](size_t bytes) {
        char* q = p;
        p += (bytes + 255) & ~size_t(255);
        return q;
    };
    unsigned short* h16 = (unsigned short*)take((size_t)N * C_FEATS * 2);
    float* es      = (float*)take((size_t)N * H_HEADS * 4);
    float* edt     = (float*)take((size_t)N * H_HEADS * 4);
    int*   deg     = (int*)take((size_t)N * 4);
    int*   offs    = (int*)take((size_t)(N + 1) * 4);
    int*   bsum    = (int*)take((size_t)NB * 4);
    int*   bpre    = (int*)take((size_t)NB * 4);
    int*   ssorted = (int*)take((size_t)E * 4);
    int*   rank    = (int*)take((size_t)E * 4);
    unsigned short* Wfh = (unsigned short*)take((size_t)C_FEATS * C_FEATS * 2);
    unsigned short* Wfl = (unsigned short*)take((size_t)C_FEATS * C_FEATS * 2);
    (void)ws_size;

    k_prep<<<8 + NB, 256, 0, stream>>>(W, Wfh, Wfl, deg, N);
    k_deg_rank<<<EB, 256, 0, stream>>>(dst, deg, rank, E);
    k_gemm<<<GB, 512, 0, stream>>>(feat, Wfh, Wfl, aw, h16, es, edt, N);
    k_bsum<<<NB, 256, 0, stream>>>(deg, bsum, N);
    k_scanb<<<1, 256, 0, stream>>>(bsum, bpre, NB, offs, N);
    k_scanc<<<NB, 256, 0, stream>>>(deg, bpre, offs, N);
    k_scatter<<<EB, 256, 0, stream>>>(src, dst, rank, offs, ssorted, E);
    k_agg<<<(N + 3) / 4, 256, 0, stream>>>(h16, es, edt, offs, ssorted, bias, out, N);
}

// Round 12
// 119.937 us; speedup vs baseline: 1.1143x; 1.1143x over previous
//
#include <hip/hip_runtime.h>
#include <hip/hip_bf16.h>

#define H_HEADS 8
#define D_OUT 16
#define C_FEATS 128          // H*D = in-feats = 128
#define NEG_SLOPE 0.2f

typedef __attribute__((ext_vector_type(8))) short short8;
typedef __attribute__((ext_vector_type(4))) float f32x4;

__device__ inline unsigned short f2bf(float f) {
    __hip_bfloat16 b = __float2bfloat16(f);
    return *reinterpret_cast<unsigned short*>(&b);
}
__device__ inline float bf2f(unsigned short u) {
    return __uint_as_float((unsigned)u << 16);
}
__device__ inline float bf_lo(unsigned u) { return __uint_as_float(u << 16); }
__device__ inline float bf_hi(unsigned u) { return __uint_as_float(u & 0xffff0000u); }

// ---------------- prologue: W -> split-bf16 fragments + degree/rank count ---
// deg must be zeroed (hipMemsetAsync) before this kernel.
__global__ __launch_bounds__(256) void k_prep_deg(const float* __restrict__ W,
                                                  unsigned short* __restrict__ Wfh,
                                                  unsigned short* __restrict__ Wfl,
                                                  const int* __restrict__ dst,
                                                  int* __restrict__ deg,
                                                  int* __restrict__ rank, int E) {
    const int b = blockIdx.x, t = threadIdx.x;
    if (b < 8) {
        const int idx = b * 256 + t;          // 0..2047 = 32 frags x 64 lanes
        const int frag = idx >> 6, lane = idx & 63;
        const int kc = frag >> 3, nt = frag & 7;
        const int kb = kc * 32 + ((lane >> 4) << 3);
        const int col = nt * 16 + (lane & 15);
        unsigned short hs[8], ls[8];
#pragma unroll
        for (int i = 0; i < 8; ++i) {
            const float x = W[(size_t)(kb + i) * C_FEATS + col];
            const unsigned short hh = f2bf(x);
            hs[i] = hh;
            ls[i] = f2bf(x - bf2f(hh));
        }
        uint4 uh, ul;
        uh.x = hs[0] | ((unsigned)hs[1] << 16);
        uh.y = hs[2] | ((unsigned)hs[3] << 16);
        uh.z = hs[4] | ((unsigned)hs[5] << 16);
        uh.w = hs[6] | ((unsigned)hs[7] << 16);
        ul.x = ls[0] | ((unsigned)ls[1] << 16);
        ul.y = ls[2] | ((unsigned)ls[3] << 16);
        ul.z = ls[4] | ((unsigned)ls[5] << 16);
        ul.w = ls[6] | ((unsigned)ls[7] << 16);
        *reinterpret_cast<uint4*>(&Wfh[(size_t)idx * 8]) = uh;
        *reinterpret_cast<uint4*>(&Wfl[(size_t)idx * 8]) = ul;
    } else {
        const int e = (b - 8) * 256 + t;
        if (e < E)
            rank[e] = atomicAdd(&deg[dst[e]], 1);
    }
}

// ---------------- per-block degree sums ----------------
__global__ void k_bsum(const int* __restrict__ deg, int* __restrict__ bsum, int N) {
    int i = blockIdx.x * 256 + threadIdx.x;
    int v = (i < N) ? deg[i] : 0;
#pragma unroll
    for (int m = 1; m < 64; m <<= 1) v += __shfl_xor(v, m, 64);
    __shared__ int ws[4];
    if ((threadIdx.x & 63) == 0) ws[threadIdx.x >> 6] = v;
    __syncthreads();
    if (threadIdx.x == 0) bsum[blockIdx.x] = ws[0] + ws[1] + ws[2] + ws[3];
}

// ---------------- scan helpers ----------------
__device__ inline int block_scan_incl(int v) {
    int lane = threadIdx.x & 63, w = threadIdx.x >> 6;
    int x = v;
#pragma unroll
    for (int d = 1; d < 64; d <<= 1) {
        int u = __shfl_up(x, d, 64);
        if (lane >= d) x += u;
    }
    __shared__ int wsum[4];
    if (lane == 63) wsum[w] = x;
    __syncthreads();
    int add = 0;
    for (int k = 0; k < w; ++k) add += wsum[k];
    return x + add;
}

__global__ void k_scanb(const int* __restrict__ bsum, int* __restrict__ bpre,
                        int NB, int* __restrict__ offs, int N) {
    int t = threadIdx.x;
    int v = (t < NB) ? bsum[t] : 0;
    int incl = block_scan_incl(v);
    if (t < NB) bpre[t] = incl - v;
    if (t == NB - 1) offs[N] = incl;
}

__global__ void k_scanc(const int* __restrict__ deg, const int* __restrict__ bpre,
                        int* __restrict__ offs, int N) {
    int i = blockIdx.x * 256 + threadIdx.x;
    int v = (i < N) ? deg[i] : 0;
    int incl = block_scan_incl(v);
    int excl = incl - v + bpre[blockIdx.x];
    if (i < N) offs[i] = excl;
}

// ---------------- MFMA GEMM (+logits epilogue) fused with scatter -----------
// Blocks [0,GB): gemm, 512 thr = 8 waves, 128 rows, W staged in LDS.
// Blocks [GB,..): atomic-free scatter (independent of gemm; overlaps).
__global__ __launch_bounds__(512) void k_gemm_scatter(
    const float* __restrict__ feat, const unsigned short* __restrict__ Wfh,
    const unsigned short* __restrict__ Wfl, const float* __restrict__ aw,
    unsigned short* __restrict__ h16, float* __restrict__ es,
    float* __restrict__ ed, const int* __restrict__ src,
    const int* __restrict__ dst, const int* __restrict__ rank,
    const int* __restrict__ offs, int* __restrict__ ssorted,
    int N, int E, int GB) {
    const int t = threadIdx.x;
    if ((int)blockIdx.x >= GB) {
        const int e = (blockIdx.x - GB) * 512 + t;
        if (e < E)
            ssorted[offs[dst[e]] + rank[e]] = src[e];
        return;
    }
    __shared__ uint4 sW[4096];                 // [0,2048): Wfh  [2048,4096): Wfl
    {
        const uint4* gh = reinterpret_cast<const uint4*>(Wfh);
        const uint4* gl = reinterpret_cast<const uint4*>(Wfl);
#pragma unroll
        for (int i = 0; i < 4; ++i) {
            const int j = t + i * 512;
            sW[j] = gh[j];
            sW[j + 2048] = gl[j];
        }
    }
    __syncthreads();

    const int bid = blockIdx.x;
    const int w = t >> 6, lane = t & 63;
    const int rbase = bid * 128 + w * 16;
    const int rowA = rbase + (lane & 15);
    const int ko = (lane >> 4) << 3;
    const bool rv = rowA < N;
    const float* fr = feat + (size_t)rowA * C_FEATS;

    f32x4 acc[8];
#pragma unroll
    for (int nt = 0; nt < 8; ++nt)
#pragma unroll
        for (int j = 0; j < 4; ++j) acc[nt][j] = 0.f;

#pragma unroll
    for (int kc = 0; kc < 4; ++kc) {
        float4 x0 = make_float4(0.f, 0.f, 0.f, 0.f), x1 = x0;
        if (rv) {
            x0 = *reinterpret_cast<const float4*>(fr + kc * 32 + ko);
            x1 = *reinterpret_cast<const float4*>(fr + kc * 32 + ko + 4);
        }
        const float xs[8] = {x0.x, x0.y, x0.z, x0.w, x1.x, x1.y, x1.z, x1.w};
        short8 ah, al;
#pragma unroll
        for (int i = 0; i < 8; ++i) {
            const unsigned short hh = f2bf(xs[i]);
            ah[i] = (short)hh;
            al[i] = (short)f2bf(xs[i] - bf2f(hh));
        }
#pragma unroll
        for (int nt = 0; nt < 8; ++nt) {
            const int fi = (kc * 8 + nt) * 64 + lane;
            const short8 bh = *reinterpret_cast<const short8*>(&sW[fi]);
            const short8 bl = *reinterpret_cast<const short8*>(&sW[fi + 2048]);
            acc[nt] = __builtin_amdgcn_mfma_f32_16x16x32_bf16(ah, bh, acc[nt], 0, 0, 0);
            acc[nt] = __builtin_amdgcn_mfma_f32_16x16x32_bf16(al, bh, acc[nt], 0, 0, 0);
            acc[nt] = __builtin_amdgcn_mfma_f32_16x16x32_bf16(ah, bl, acc[nt], 0, 0, 0);
        }
    }
    // C layout (verified): col = lane&15, row = (lane>>4)*4 + reg
    const int r0 = rbase + ((lane >> 4) << 2);
    const int colc = lane & 15;
#pragma unroll
    for (int nt = 0; nt < 8; ++nt) {
#pragma unroll
        for (int r = 0; r < 4; ++r) {
            const int row = r0 + r;
            if (row < N)
                h16[(size_t)row * C_FEATS + nt * 16 + colc] = f2bf(acc[nt][r]);
        }
    }
    // logits epilogue: es/ed[row, nt] = sum_d acc-col-group * aw
#pragma unroll
    for (int nt = 0; nt < 8; ++nt) {
        const float wa = aw[nt * 16 + colc];
        const float wb = aw[C_FEATS + nt * 16 + colc];
#pragma unroll
        for (int r = 0; r < 4; ++r) {
            float pe = acc[nt][r] * wa;
            float pd = acc[nt][r] * wb;
#pragma unroll
            for (int msk = 1; msk <= 8; msk <<= 1) {
                pe += __shfl_xor(pe, msk, 64);
                pd += __shfl_xor(pd, msk, 64);
            }
            const int row = r0 + r;
            if (colc == 0 && row < N) {
                es[(size_t)row * H_HEADS + nt] = pe;
                ed[(size_t)row * H_HEADS + nt] = pd;
            }
        }
    }
}

// ---------------- two-pass softmax + aggregation ----------------
// One wave per node. deg<=32 fast path: batch structure for MLP —
// (1) 4 coalesced sn loads, (2) 4 independent es gathers, (3) closed-form
// softmax (4 exp/lane), (4) ALL h16 uint4 gathers issued back-to-back into
// hv[8] (static unrolled), (5) fma consume. deg>32: proven streaming path.
__global__ __launch_bounds__(256) void k_agg(const unsigned short* __restrict__ h16,
                                             const float* __restrict__ es,
                                             const float* __restrict__ ed,
                                             const int* __restrict__ offs,
                                             const int* __restrict__ ssorted,
                                             const float* __restrict__ bias,
                                             float* __restrict__ out, int N) {
    const int wid = threadIdx.x >> 6, lane = threadIdx.x & 63;
    const int n = blockIdx.x * 4 + wid;
    if (n >= N) return;
    const int beg = offs[n];
    const int deg = offs[n + 1] - beg;

    const int hh = lane >> 3, j0 = lane & 7;
    const float edv = ed[(size_t)n * H_HEADS + hh];

    const int cl = lane & 15, q = lane >> 4;
    const int ah = cl >> 1;             // head owning this lane's 8 columns
    const int ab = ah << 3;             // softmax-layout base lane for head ah
    float acc[8];
#pragma unroll
    for (int k = 0; k < 8; ++k) acc[k] = 0.f;

    if (deg <= 32) {
        // ---- batch-MLP fast path ----
        int snc[4];
#pragma unroll
        for (int c = 0; c < 4; ++c) {
            const int j = c * 8 + j0;
            snc[c] = (j < deg) ? ssorted[beg + j] : 0;
        }
        float evc[4];
#pragma unroll
        for (int c = 0; c < 4; ++c) {
            const int j = c * 8 + j0;
            if (j < deg) {
                float tv = es[(size_t)snc[c] * H_HEADS + hh] + edv;
                evc[c] = tv > 0.f ? tv : NEG_SLOPE * tv;
            } else {
                evc[c] = -1e30f;
            }
        }
        float m = fmaxf(fmaxf(evc[0], evc[1]), fmaxf(evc[2], evc[3]));
#pragma unroll
        for (int msk = 1; msk < 8; msk <<= 1)
            m = fmaxf(m, __shfl_xor(m, msk, 64));
        const float t0 = __expf(evc[0] - m), t1 = __expf(evc[1] - m);
        const float t2 = __expf(evc[2] - m), t3 = __expf(evc[3] - m);
        float s = t0 + t1 + t2 + t3;
#pragma unroll
        for (int msk = 1; msk < 8; msk <<= 1)
            s += __shfl_xor(s, msk, 64);
        const float inv = (s > 0.f) ? 1.f / s : 0.f;
        const float alc[4] = {t0 * inv, t1 * inv, t2 * inv, t3 * inv};

        uint4 hv[8];
        float alv[8];
#pragma unroll
        for (int c = 0; c < 4; ++c) {
#pragma unroll
            for (int e4 = 0; e4 < 2; ++e4) {
                const int idx = c * 2 + e4;
                const int base = c * 8 + e4 * 4;
                if (base < deg) {                 // wave-uniform
                    const int s0 = __shfl(snc[c], 4 * e4 + 0, 64);
                    const int s1 = __shfl(snc[c], 4 * e4 + 1, 64);
                    const int s2 = __shfl(snc[c], 4 * e4 + 2, 64);
                    const int s3 = __shfl(snc[c], 4 * e4 + 3, 64);
                    const int snq = (q == 0) ? s0 : (q == 1) ? s1 : (q == 2) ? s2 : s3;
                    alv[idx] = __shfl(alc[c], ab + 4 * e4 + q, 64);
                    hv[idx] = *reinterpret_cast<const uint4*>(
                        &h16[(size_t)snq * C_FEATS + cl * 8]);
                }
            }
        }
#pragma unroll
        for (int c = 0; c < 4; ++c) {
#pragma unroll
            for (int e4 = 0; e4 < 2; ++e4) {
                const int idx = c * 2 + e4;
                const int base = c * 8 + e4 * 4;
                if (base < deg) {
                    const float al = alv[idx];
                    acc[0] = fmaf(al, bf_lo(hv[idx].x), acc[0]);
                    acc[1] = fmaf(al, bf_hi(hv[idx].x), acc[1]);
                    acc[2] = fmaf(al, bf_lo(hv[idx].y), acc[2]);
                    acc[3] = fmaf(al, bf_hi(hv[idx].y), acc[3]);
                    acc[4] = fmaf(al, bf_lo(hv[idx].z), acc[4]);
                    acc[5] = fmaf(al, bf_hi(hv[idx].z), acc[5]);
                    acc[6] = fmaf(al, bf_lo(hv[idx].w), acc[6]);
                    acc[7] = fmaf(al, bf_hi(hv[idx].w), acc[7]);
                }
            }
        }
    } else {
        // ---------- streaming fallback (proven) ----------
        float m = -1e30f, s = 0.f;
        for (int e = j0; e < deg; e += 8) {
            int sn = ssorted[beg + e];
            float ev = es[(size_t)sn * H_HEADS + hh] + edv;
            ev = ev > 0.f ? ev : NEG_SLOPE * ev;
            if (ev > m) {
                s = s * __expf(m - ev) + 1.f;
                m = ev;
            } else {
                s += __expf(ev - m);
            }
        }
#pragma unroll
        for (int msk = 1; msk < 8; msk <<= 1) {
            float mo = __shfl_xor(m, msk, 64);
            float so = __shfl_xor(s, msk, 64);
            float mn = fmaxf(m, mo);
            s = s * __expf(m - mn) + so * __expf(mo - mn);
            m = mn;
        }
        const float inv = (s > 0.f) ? 1.f / s : 0.f;

        for (int cb = 0; cb < deg; cb += 8) {
            const int j = cb + j0;
            int sn = 0;
            float alpha = 0.f;
            if (j < deg) {
                sn = ssorted[beg + j];
                float tv = es[(size_t)sn * H_HEADS + hh] + edv;
                tv = tv > 0.f ? tv : NEG_SLOPE * tv;
                alpha = __expf(tv - m) * inv;
            }
            int rem = deg - cb; if (rem > 8) rem = 8;
#pragma unroll
            for (int e4 = 0; e4 < 2; ++e4) {
                if (4 * e4 >= rem) break;
                const int s0 = __shfl(sn, 4 * e4 + 0, 64);
                const int s1 = __shfl(sn, 4 * e4 + 1, 64);
                const int s2 = __shfl(sn, 4 * e4 + 2, 64);
                const int s3 = __shfl(sn, 4 * e4 + 3, 64);
                const int snq = (q == 0) ? s0 : (q == 1) ? s1 : (q == 2) ? s2 : s3;
                const float al = __shfl(alpha, ab + 4 * e4 + q, 64);
                const uint4 hv = *reinterpret_cast<const uint4*>(
                    &h16[(size_t)snq * C_FEATS + cl * 8]);
                acc[0] = fmaf(al, bf_lo(hv.x), acc[0]);
                acc[1] = fmaf(al, bf_hi(hv.x), acc[1]);
                acc[2] = fmaf(al, bf_lo(hv.y), acc[2]);
                acc[3] = fmaf(al, bf_hi(hv.y), acc[3]);
                acc[4] = fmaf(al, bf_lo(hv.z), acc[4]);
                acc[5] = fmaf(al, bf_hi(hv.z), acc[5]);
                acc[6] = fmaf(al, bf_lo(hv.w), acc[6]);
                acc[7] = fmaf(al, bf_hi(hv.w), acc[7]);
            }
        }
    }

#pragma unroll
    for (int k = 0; k < 8; ++k) {
        acc[k] += __shfl_xor(acc[k], 16, 64);
        acc[k] += __shfl_xor(acc[k], 32, 64);
    }
    if (q == 0) {
        const float4 b0 = *reinterpret_cast<const float4*>(&bias[cl * 8]);
        const float4 b1 = *reinterpret_cast<const float4*>(&bias[cl * 8 + 4]);
        float4 o0 = make_float4(acc[0] + b0.x, acc[1] + b0.y, acc[2] + b0.z, acc[3] + b0.w);
        float4 o1 = make_float4(acc[4] + b1.x, acc[5] + b1.y, acc[6] + b1.z, acc[7] + b1.w);
        *reinterpret_cast<float4*>(&out[(size_t)n * C_FEATS + cl * 8]) = o0;
        *reinterpret_cast<float4*>(&out[(size_t)n * C_FEATS + cl * 8 + 4]) = o1;
    }
}

extern "C" void kernel_launch(void* const* d_in, const int* in_sizes, int n_in,
                              void* d_out, int out_size, void* d_ws, size_t ws_size,
                              hipStream_t stream) {
    const float* feat = (const float*)d_in[0];
    const float* W    = (const float*)d_in[1];
    const float* aw   = (const float*)d_in[2];
    const float* bias = (const float*)d_in[3];
    const int*   src  = (const int*)d_in[4];
    const int*   dst  = (const int*)d_in[5];
    float* out = (float*)d_out;

    const int N = in_sizes[0] / C_FEATS;
    const int E = in_sizes[4];
    const int NB = (N + 255) / 256;          // 196 (<= 256 for k_scanb)
    const int GB = (N + 127) / 128;          // gemm blocks (391)
    const int EB = (E + 255) / 256;          // edge blocks @256 (3125)
    const int EB2 = (E + 511) / 512;         // edge blocks @512 (1563)

    char* p = (char*)d_ws;
    auto take = [&](size_t bytes) {
        char* q = p;
        p += (bytes + 255) & ~size_t(255);
        return q;
    };
    unsigned short* h16 = (unsigned short*)take((size_t)N * C_FEATS * 2);
    float* es      = (float*)take((size_t)N * H_HEADS * 4);
    float* edt     = (float*)take((size_t)N * H_HEADS * 4);
    int*   deg     = (int*)take((size_t)N * 4);
    int*   offs    = (int*)take((size_t)(N + 1) * 4);
    int*   bsum    = (int*)take((size_t)NB * 4);
    int*   bpre    = (int*)take((size_t)NB * 4);
    int*   ssorted = (int*)take((size_t)E * 4);
    int*   rank    = (int*)take((size_t)E * 4);
    unsigned short* Wfh = (unsigned short*)take((size_t)C_FEATS * C_FEATS * 2);
    unsigned short* Wfl = (unsigned short*)take((size_t)C_FEATS * C_FEATS * 2);
    (void)ws_size;

    hipMemsetAsync(deg, 0, (size_t)N * 4, stream);
    k_prep_deg<<<8 + EB, 256, 0, stream>>>(W, Wfh, Wfl, dst, deg, rank, E);
    k_bsum<<<NB, 256, 0, stream>>>(deg, bsum, N);
    k_scanb<<<1, 256, 0, stream>>>(bsum, bpre, NB, offs, N);
    k_scanc<<<NB, 256, 0, stream>>>(deg, bpre, offs, N);
    k_gemm_scatter<<<GB + EB2, 512, 0, stream>>>(feat, Wfh, Wfl, aw, h16, es, edt,
                                                 src, dst, rank, offs, ssorted,
                                                 N, E, GB);
    k_agg<<<(N + 3) / 4, 256, 0, stream>>>(h16, es, edt, offs, ssorted, bias, out, N);
}